// Round 1
// baseline (1026.176 us; speedup 1.0000x reference)
//
#include <hip/hip_runtime.h>

#define N_NODES 50000
#define N_EDGES 800000
#define IN_DIM  1024
#define COUT    127
#define KPAD1   128
#define H1      256
#define H2      128
#define MBLK    782          // ceil(50000/64); 782*64 = 50048

// ---------------- conv1d: h[N,1024] -> x1[N,128] (col 127 = 0 pad) ----------
__global__ void conv_kernel(const float* __restrict__ h, const float* __restrict__ w,
                            const float* __restrict__ b, float* __restrict__ x1) {
    int n = blockIdx.x;
    int t = threadIdx.x;
    const float* hr = h + (size_t)n * IN_DIM;
    if (t < COUT) {
        const float* p = hr + t * 8;              // 32B aligned
        float4 a = *(const float4*)p;
        float4 c = *(const float4*)(p + 4);
        float2 d = *(const float2*)(p + 8);
        float s = b[0];
        s += a.x * w[0] + a.y * w[1] + a.z * w[2] + a.w * w[3];
        s += c.x * w[4] + c.y * w[5] + c.z * w[6] + c.w * w[7];
        s += d.x * w[8] + d.y * w[9];
        x1[(size_t)n * KPAD1 + t] = fmaxf(s, 0.f);
    } else {
        x1[(size_t)n * KPAD1 + t] = 0.f;          // zero pad column 127
    }
}

// ---------------- CSR build ----------------
__global__ void deg_kernel(const int* __restrict__ dst, int* __restrict__ deg) {
    int e = blockIdx.x * blockDim.x + threadIdx.x;
    if (e < N_EDGES) atomicAdd(&deg[dst[e]], 1);
}

__global__ __launch_bounds__(1024) void scan_kernel(const int* __restrict__ deg,
                                                    int* __restrict__ rowptr,
                                                    int* __restrict__ cursor) {
    __shared__ int wsum[16];
    __shared__ int carry_s;
    int tid = threadIdx.x;
    int lane = tid & 63, wid = tid >> 6;
    if (tid == 0) carry_s = 0;
    __syncthreads();
    for (int base = 0; base < N_NODES; base += 1024) {
        int i = base + tid;
        int v = (i < N_NODES) ? deg[i] : 0;
        int s = v;
        #pragma unroll
        for (int off = 1; off < 64; off <<= 1) {
            int t = __shfl_up(s, off);
            if (lane >= off) s += t;
        }
        if (lane == 63) wsum[wid] = s;
        __syncthreads();
        if (tid < 16) {
            int ws = wsum[tid];
            #pragma unroll
            for (int off = 1; off < 16; off <<= 1) {
                int t = __shfl_up(ws, off);
                if (tid >= off) ws += t;
            }
            wsum[tid] = ws;                        // inclusive scan of wave sums
        }
        __syncthreads();
        int wpre = (wid == 0) ? 0 : wsum[wid - 1];
        int excl = carry_s + wpre + (s - v);
        if (i < N_NODES) { rowptr[i] = excl; cursor[i] = excl; }
        int tot = wsum[15];
        __syncthreads();
        if (tid == 0) carry_s += tot;
        __syncthreads();
    }
    if (tid == 0) rowptr[N_NODES] = carry_s;       // == E
}

__global__ void fill_kernel(const int* __restrict__ src, const int* __restrict__ dst,
                            int* __restrict__ cursor, int* __restrict__ esrc) {
    int e = blockIdx.x * blockDim.x + threadIdx.x;
    if (e < N_EDGES) {
        int d = dst[e];
        int pos = atomicAdd(&cursor[d], 1);
        esrc[pos] = src[e];
    }
}

// ---------------- mean aggregation (gather over CSR) ----------------
template <int LDX>
__global__ void agg_kernel(const float* __restrict__ X, const int* __restrict__ rowptr,
                           const int* __restrict__ esrc, float* __restrict__ out) {
    int n = blockIdx.x;
    int f = threadIdx.x;                           // blockDim.x == LDX
    int s0 = rowptr[n], s1 = rowptr[n + 1];
    float acc = 0.f;
    for (int e = s0; e < s1; ++e) {
        int sidx = esrc[e];
        acc += X[(size_t)sidx * LDX + f];
    }
    float dnm = (float)max(s1 - s0, 1);
    out[(size_t)n * LDX + f] = acc / dnm;
}

// ---------------- pad SAGE1 weights 127x256 -> 128x256 (row 127 = 0) --------
__global__ void padw_kernel(const float* __restrict__ ws, const float* __restrict__ wn,
                            float* __restrict__ wsp, float* __restrict__ wnp) {
    int i = blockIdx.x * blockDim.x + threadIdx.x; // 0 .. 128*256-1
    int row = i >> 8;
    float vs = 0.f, vn = 0.f;
    if (row < COUT) { vs = ws[i]; vn = wn[i]; }
    wsp[i] = vs;
    wnp[i] = vn;
}

// ---------------- fused SAGE GEMM: out = relu(X@Ws + A@Wn + b) --------------
// KDIM = K (also row stride of X/A), HOUT = output cols (also W row stride).
// POOL: instead of storing rows, relu + column-sum over nodes -> atomicAdd hg.
template <int KDIM, int HOUT, bool POOL>
__global__ __launch_bounds__(256) void sage_gemm(
        const float* __restrict__ X, const float* __restrict__ A,
        const float* __restrict__ Wself, const float* __restrict__ Wneigh,
        const float* __restrict__ bias, float* __restrict__ out) {
    __shared__ float AsX[32][68], AsA[32][68], BsS[32][68], BsN[32][68];
    int tid = threadIdx.x;
    int tx = tid & 15, ty = tid >> 4;
    int m0 = blockIdx.x * 64;
    int j0 = blockIdx.y * 64;
    float acc[4][4] = {};

    int lr = tid >> 2;            // A-tile: row 0..63
    int lc = (tid & 3) << 2;      // A-tile: k col {0,4,8,12} (+16 for 2nd f4)
    int br = tid >> 4;            // B-tile: k row 0..15 (+16)
    int bc = (tid & 15) << 2;     // B-tile: col 0..60

    for (int k0 = 0; k0 < KDIM; k0 += 32) {
        int gr = m0 + lr;
        float4 xv0, xv1, av0, av1;
        if (gr < N_NODES) {
            const float* xp = X + (size_t)gr * KDIM + k0 + lc;
            const float* ap = A + (size_t)gr * KDIM + k0 + lc;
            xv0 = *(const float4*)xp;        xv1 = *(const float4*)(xp + 16);
            av0 = *(const float4*)ap;        av1 = *(const float4*)(ap + 16);
        } else {
            xv0 = xv1 = av0 = av1 = make_float4(0.f, 0.f, 0.f, 0.f);
        }
        const float* bsp = Wself  + (size_t)(k0 + br) * HOUT + j0 + bc;
        const float* bnp = Wneigh + (size_t)(k0 + br) * HOUT + j0 + bc;
        float4 bs0 = *(const float4*)bsp;
        float4 bs1 = *(const float4*)(bsp + 16 * HOUT);
        float4 bn0 = *(const float4*)bnp;
        float4 bn1 = *(const float4*)(bnp + 16 * HOUT);

        __syncthreads();                           // protect prior-iter LDS reads
        AsX[lc + 0][lr] = xv0.x;  AsX[lc + 1][lr] = xv0.y;
        AsX[lc + 2][lr] = xv0.z;  AsX[lc + 3][lr] = xv0.w;
        AsX[lc + 16][lr] = xv1.x; AsX[lc + 17][lr] = xv1.y;
        AsX[lc + 18][lr] = xv1.z; AsX[lc + 19][lr] = xv1.w;
        AsA[lc + 0][lr] = av0.x;  AsA[lc + 1][lr] = av0.y;
        AsA[lc + 2][lr] = av0.z;  AsA[lc + 3][lr] = av0.w;
        AsA[lc + 16][lr] = av1.x; AsA[lc + 17][lr] = av1.y;
        AsA[lc + 18][lr] = av1.z; AsA[lc + 19][lr] = av1.w;
        *(float4*)&BsS[br][bc]      = bs0;
        *(float4*)&BsS[br + 16][bc] = bs1;
        *(float4*)&BsN[br][bc]      = bn0;
        *(float4*)&BsN[br + 16][bc] = bn1;
        __syncthreads();

        #pragma unroll
        for (int kk = 0; kk < 32; ++kk) {
            float4 ax4 = *(float4*)&AsX[kk][ty * 4];
            float4 aa4 = *(float4*)&AsA[kk][ty * 4];
            float4 bs4 = *(float4*)&BsS[kk][tx * 4];
            float4 bn4 = *(float4*)&BsN[kk][tx * 4];
            float axr[4] = {ax4.x, ax4.y, ax4.z, ax4.w};
            float aar[4] = {aa4.x, aa4.y, aa4.z, aa4.w};
            float bsr[4] = {bs4.x, bs4.y, bs4.z, bs4.w};
            float bnr[4] = {bn4.x, bn4.y, bn4.z, bn4.w};
            #pragma unroll
            for (int i = 0; i < 4; ++i)
                #pragma unroll
                for (int j = 0; j < 4; ++j)
                    acc[i][j] += axr[i] * bsr[j] + aar[i] * bnr[j];
        }
    }

    const float4 bv = *(const float4*)&bias[j0 + tx * 4];
    if constexpr (!POOL) {
        #pragma unroll
        for (int i = 0; i < 4; ++i) {
            int gr = m0 + ty * 4 + i;
            if (gr < N_NODES) {
                float4 o;
                o.x = fmaxf(acc[i][0] + bv.x, 0.f);
                o.y = fmaxf(acc[i][1] + bv.y, 0.f);
                o.z = fmaxf(acc[i][2] + bv.z, 0.f);
                o.w = fmaxf(acc[i][3] + bv.w, 0.f);
                *(float4*)&out[(size_t)gr * HOUT + j0 + tx * 4] = o;
            }
        }
    } else {
        float cs[4] = {0.f, 0.f, 0.f, 0.f};
        #pragma unroll
        for (int i = 0; i < 4; ++i) {
            int gr = m0 + ty * 4 + i;
            if (gr < N_NODES) {
                cs[0] += fmaxf(acc[i][0] + bv.x, 0.f);
                cs[1] += fmaxf(acc[i][1] + bv.y, 0.f);
                cs[2] += fmaxf(acc[i][2] + bv.z, 0.f);
                cs[3] += fmaxf(acc[i][3] + bv.w, 0.f);
            }
        }
        __syncthreads();                           // reuse AsX as reduction pad
        float* red = &AsX[0][0];                   // 16 x 64 floats
        red[ty * 64 + tx * 4 + 0] = cs[0];
        red[ty * 64 + tx * 4 + 1] = cs[1];
        red[ty * 64 + tx * 4 + 2] = cs[2];
        red[ty * 64 + tx * 4 + 3] = cs[3];
        __syncthreads();
        if (ty == 0) {
            #pragma unroll
            for (int jj = 0; jj < 4; ++jj) {
                float s = 0.f;
                #pragma unroll
                for (int r = 0; r < 16; ++r) s += red[r * 64 + tx * 4 + jj];
                atomicAdd(&out[j0 + tx * 4 + jj], s);
            }
        }
    }
}

// ---------------- mean + MLP head (single block) ----------------
__global__ void mlp_kernel(const float* __restrict__ hg,
                           const float* __restrict__ f1w, const float* __restrict__ f1b,
                           const float* __restrict__ f2w, const float* __restrict__ f2b,
                           const float* __restrict__ f3w, const float* __restrict__ f3b,
                           float* __restrict__ out) {
    __shared__ float h0[128], y1[64], y2[32];
    int t = threadIdx.x;
    if (t < 128) h0[t] = hg[t] * (1.0f / N_NODES);
    __syncthreads();
    if (t < 64) {
        float s = f1b[t];
        for (int k = 0; k < 128; ++k) s += h0[k] * f1w[k * 64 + t];
        y1[t] = fmaxf(s, 0.f);
    }
    __syncthreads();
    if (t < 32) {
        float s = f2b[t];
        for (int k = 0; k < 64; ++k) s += y1[k] * f2w[k * 32 + t];
        y2[t] = fmaxf(s, 0.f);
    }
    __syncthreads();
    if (t == 0) {
        float s = f3b[0];
        for (int k = 0; k < 32; ++k) s += y2[k] * f3w[k];
        out[0] = s;
    }
}

extern "C" void kernel_launch(void* const* d_in, const int* in_sizes, int n_in,
                              void* d_out, int out_size, void* d_ws, size_t ws_size,
                              hipStream_t stream) {
    (void)in_sizes; (void)n_in; (void)out_size; (void)ws_size;
    const float* h        = (const float*)d_in[0];
    const int*   src      = (const int*)d_in[1];
    const int*   dst      = (const int*)d_in[2];
    const float* cw       = (const float*)d_in[3];
    const float* cb       = (const float*)d_in[4];
    const float* w_self1  = (const float*)d_in[5];
    const float* w_neigh1 = (const float*)d_in[6];
    const float* b1       = (const float*)d_in[7];
    const float* w_self2  = (const float*)d_in[8];
    const float* w_neigh2 = (const float*)d_in[9];
    const float* b2       = (const float*)d_in[10];
    const float* f1w      = (const float*)d_in[11];
    const float* f1b      = (const float*)d_in[12];
    const float* f2w      = (const float*)d_in[13];
    const float* f2b      = (const float*)d_in[14];
    const float* f3w      = (const float*)d_in[15];
    const float* f3b      = (const float*)d_in[16];
    float* out = (float*)d_out;

    // workspace layout (bytes, 256-aligned); agg2 overlays x1+agg1 (dead after GEMM1)
    char* ws = (char*)d_ws;
    float* x1    = (float*)(ws + 0);           // 50048*128*4 = 25,624,576
    float* agg1  = (float*)(ws + 25624576);    // 25,624,576
    float* agg2  = (float*)(ws + 0);           // 50048*256*4 = 51,249,152 (overlay)
    float* x2    = (float*)(ws + 51249152);    // 51,249,152
    float* wsp1  = (float*)(ws + 102498304);   // 131,072
    float* wnp1  = (float*)(ws + 102629376);   // 131,072
    int*   deg   = (int*)  (ws + 102760448);   // 200,192
    int*   rowp  = (int*)  (ws + 102960640);   // 200,448
    int*   cur   = (int*)  (ws + 103161088);   // 200,192
    int*   esrc  = (int*)  (ws + 103361280);   // 3,200,000
    float* hg    = (float*)(ws + 106561280);   // 512    (total ~106.6 MB)

    hipMemsetAsync(deg, 0, N_NODES * sizeof(int), stream);
    hipMemsetAsync(hg, 0, 128 * sizeof(float), stream);

    padw_kernel<<<128, 256, 0, stream>>>(w_self1, w_neigh1, wsp1, wnp1);
    deg_kernel<<<(N_EDGES + 255) / 256, 256, 0, stream>>>(dst, deg);
    scan_kernel<<<1, 1024, 0, stream>>>(deg, rowp, cur);
    fill_kernel<<<(N_EDGES + 255) / 256, 256, 0, stream>>>(src, dst, cur, esrc);
    conv_kernel<<<N_NODES, 128, 0, stream>>>(h, cw, cb, x1);
    agg_kernel<128><<<N_NODES, 128, 0, stream>>>(x1, rowp, esrc, agg1);
    dim3 g1(MBLK, H1 / 64);
    sage_gemm<KPAD1, H1, false><<<g1, 256, 0, stream>>>(x1, agg1, wsp1, wnp1, b1, x2);
    agg_kernel<256><<<N_NODES, 256, 0, stream>>>(x2, rowp, esrc, agg2);
    dim3 g2(MBLK, H2 / 64);
    sage_gemm<H1, H2, true><<<g2, 256, 0, stream>>>(x2, agg2, w_self2, w_neigh2, b2, hg);
    mlp_kernel<<<1, 128, 0, stream>>>(hg, f1w, f1b, f2w, f2b, f3w, f3b, out);
}